// Round 4
// baseline (810.606 us; speedup 1.0000x reference)
//
#include <hip/hip_runtime.h>
#include <hip/hip_bf16.h>
#include <cstdint>
#include <cstddef>

#define N_F 128
#define N_HOPS 8
#define N_HID 256
#define N_CLS 64

typedef __bf16 bf16;
typedef __attribute__((ext_vector_type(8))) __bf16 bf16x8;
typedef __attribute__((ext_vector_type(4))) float f32x4;

__device__ inline f32x4 mfma16(bf16x8 a, bf16x8 b, f32x4 c) {
    return __builtin_amdgcn_mfma_f32_16x16x32_bf16(a, b, c, 0, 0, 0);
}

// ---------------------------------------------------------------------------
// Weight packing into MFMA B-operand fragment frames.
// Frame f = kt*NT + nt holds B[kt*32 .. +32)[nt*16 .. +16):
//   element (lane, j) = W[kt*32 + (lane>>4)*8 + j][nt*16 + (lane&15)]
// stored at d[(f*64 + lane)*8 + j].
// ---------------------------------------------------------------------------
__device__ inline void pack_one(const float* __restrict__ s, bf16* __restrict__ d,
                                int NC, int ntn, int idx) {
    const int lane = idx & 63;
    const int f = idx >> 6;
    const int kt = f / ntn, nt = f - kt * ntn;
    const int krow = kt * 32 + ((lane >> 4) << 3);
    const int col = nt * 16 + (lane & 15);
    const float* ss = s + (size_t)krow * NC + col;
    bf16* dd = d + ((size_t)f * 64 + lane) * 8;
#pragma unroll
    for (int j = 0; j < 8; ++j) dd[j] = (bf16)ss[(size_t)j * NC];
}

__global__ void pack_weights(const float* __restrict__ W1, const float* __restrict__ W2,
                             const float* __restrict__ O1, const float* __restrict__ O2,
                             bf16* p1, bf16* p2, bf16* p3, bf16* p4) {
    int i = blockIdx.x * 256 + threadIdx.x;
    if (i < 32768) { pack_one(W1, p1, 256, 16, i); return; }   // 1024x256: 512 frames
    i -= 32768;
    if (i < 8192)  { pack_one(W2, p2, 256, 16, i); return; }   // 256x256: 128 frames
    i -= 8192;
    if (i < 4096)  { pack_one(O1, p3, 256, 16, i); return; }   // 128x256: 64 frames
    i -= 4096;
    if (i < 2048)  { pack_one(O2, p4, 64, 4, i); return; }     // 256x64: 32 frames
}

// C-layout->A-frag scatter: H[row][col] -> frame ((col>>5)*4 + row>>4),
// lane' = (row&15) | (((col>>3)&3)<<4), elem = col&7.  (derived from the two
// HW-verified layouts: C col=lane&15,row=quad*4+r; A lane=m|(q<<4) holds k=q*8+j)
__device__ __forceinline__ int frag_addr(int row, int col) {
    return (((col >> 5) << 2) + (row >> 4)) * 512 + (((row & 15) | (((col >> 3) & 3) << 4)) << 3) + (col & 7);
}

// ---------------------------------------------------------------------------
// K1: 64 rows/block, 256 thr (4 waves; wave wc -> cols [wc*64,+64)).
// GEMM1 K-loop is barrier-free: each wave loads its A-fragments DIRECTLY from
// global (fp32->bf16 in-register) and B-fragments directly from the packed
// frames (L2-resident). s_x: wave wc owns hops {2wc,2wc+1}, plain LDS stores.
// h1 -> LDS in A-frag order; GEMM2 B direct from w2p; softmax as verified.
// ---------------------------------------------------------------------------
__global__ __launch_bounds__(256) void k1_kernel(
    const float* __restrict__ feats, const bf16* __restrict__ w1p, const bf16* __restrict__ w2p,
    const float* __restrict__ b1, const float* __restrict__ b2,
    const float* __restrict__ a_jk_p, const float* __restrict__ a_main_p,
    const float* __restrict__ wref, const float* __restrict__ wax,
    const float* __restrict__ batt_p,
    float* __restrict__ wsm, int N)
{
    __shared__ bf16 Hf[32 * 512];    // 32 frames (kt*4+i) x 64 lanes x 8 = 32 KB
    __shared__ float sx[64 * 8];
    __shared__ float sref[64];

    const int t = threadIdx.x;
    const int lane = t & 63;
    const int wc = t >> 6;
    const int row0 = blockIdx.x * 64;
    const int m = lane & 15, q = lane >> 4;

    if (t < 64) sref[t] = 0.f;

    size_t rbase[4];
#pragma unroll
    for (int i = 0; i < 4; ++i) {
        const int r = min(row0 + (i << 4) + m, N - 1);
        rbase[i] = (size_t)r * N_F;
    }

    f32x4 acc[4][4] = {};
    float pacc[4] = {};

    for (int kt = 0; kt < 32; ++kt) {
        const int h = kt >> 2;
        const int f0 = ((kt & 3) << 5) + (q << 3);
        const size_t hoff = (size_t)h * N * N_F;
        // ---- A fragments: direct global load + cvt ----
        bf16x8 af[4];
        float4 v0s[4], v1s[4];
#pragma unroll
        for (int i = 0; i < 4; ++i) {
            const float* p = feats + hoff + rbase[i] + f0;
            const float4 v0 = *(const float4*)p;
            const float4 v1 = *(const float4*)(p + 4);
            v0s[i] = v0; v1s[i] = v1;
            af[i][0] = (bf16)v0.x; af[i][1] = (bf16)v0.y; af[i][2] = (bf16)v0.z; af[i][3] = (bf16)v0.w;
            af[i][4] = (bf16)v1.x; af[i][5] = (bf16)v1.y; af[i][6] = (bf16)v1.z; af[i][7] = (bf16)v1.w;
        }
        // ---- B fragments: direct from packed frames (L2) ----
        bf16x8 bfr[4];
#pragma unroll
        for (int j = 0; j < 4; ++j)
            bfr[j] = *(const bf16x8*)&w1p[((size_t)((kt << 4) + (wc << 2) + j) * 64 + lane) * 8];
#pragma unroll
        for (int i = 0; i < 4; ++i)
#pragma unroll
            for (int j = 0; j < 4; ++j)
                acc[i][j] = mfma16(af[i], bfr[j], acc[i][j]);
        // ---- s_x for this wave's own hops (wave-uniform branch) ----
        if ((kt >> 3) == wc) {
#pragma unroll
            for (int i = 0; i < 4; ++i) {
                const float4 v0 = v0s[i], v1 = v1s[i];
                pacc[i] += v0.x * wax[f0]     + v0.y * wax[f0 + 1] + v0.z * wax[f0 + 2] + v0.w * wax[f0 + 3]
                         + v1.x * wax[f0 + 4] + v1.y * wax[f0 + 5] + v1.z * wax[f0 + 6] + v1.w * wax[f0 + 7];
            }
            if ((kt & 3) == 3) {
#pragma unroll
                for (int i = 0; i < 4; ++i) {
                    float v = pacc[i];
                    v += __shfl_xor(v, 16);
                    v += __shfl_xor(v, 32);
                    if (lane < 16) sx[(((i << 4) + lane) << 3) + h] = v;  // single writer
                    pacc[i] = 0.f;
                }
            }
        }
    }

    // ---- epilogue 1: h1 = prelu(acc + b1, a_jk) -> Hf (A-frag order) ----
    const float ajk = *a_jk_p;
#pragma unroll
    for (int j = 0; j < 4; ++j) {
        const int colg = (wc << 6) + (j << 4) + m;
        const float bias = b1[colg];
#pragma unroll
        for (int i = 0; i < 4; ++i)
#pragma unroll
            for (int r = 0; r < 4; ++r) {
                const int row = (i << 4) + (q << 2) + r;
                float v = acc[i][j][r] + bias;
                v = v >= 0.f ? v : ajk * v;
                Hf[frag_addr(row, colg)] = (bf16)v;
            }
    }
    __syncthreads();

    // ---- GEMM2: jk = prelu(h1 @ W2 + b2, a_main); s_ref partials ----
    f32x4 acc2[4][4] = {};
    for (int kt = 0; kt < 8; ++kt) {
        bf16x8 af[4], bfr[4];
#pragma unroll
        for (int i = 0; i < 4; ++i)
            af[i] = *(bf16x8*)&Hf[(((kt << 2) + i) << 9) + (lane << 3)];
#pragma unroll
        for (int j = 0; j < 4; ++j)
            bfr[j] = *(const bf16x8*)&w2p[((size_t)((kt << 4) + (wc << 2) + j) * 64 + lane) * 8];
#pragma unroll
        for (int i = 0; i < 4; ++i)
#pragma unroll
            for (int j = 0; j < 4; ++j)
                acc2[i][j] = mfma16(af[i], bfr[j], acc2[i][j]);
    }

    const float amain = *a_main_p;
    float pr[4][4] = {};
#pragma unroll
    for (int j = 0; j < 4; ++j) {
        const int colg = (wc << 6) + (j << 4) + m;
        const float bias = b2[colg];
        const float wr_ = wref[colg];
#pragma unroll
        for (int i = 0; i < 4; ++i)
#pragma unroll
            for (int r = 0; r < 4; ++r) {
                float v = acc2[i][j][r] + bias;
                v = v >= 0.f ? v : amain * v;
                pr[i][r] += v * wr_;
            }
    }
#pragma unroll
    for (int mk = 1; mk < 16; mk <<= 1)
#pragma unroll
        for (int i = 0; i < 4; ++i)
#pragma unroll
            for (int r = 0; r < 4; ++r)
                pr[i][r] += __shfl_xor(pr[i][r], mk, 64);
    if (m == 0) {
#pragma unroll
        for (int i = 0; i < 4; ++i)
#pragma unroll
            for (int r = 0; r < 4; ++r)
                atomicAdd(&sref[(i << 4) + (q << 2) + r], pr[i][r]);
    }
    __syncthreads();

    // ---- scores -> sigmoid -> softmax over hops -> wsm ----
    if (t < 64) {
        const int rg = row0 + t;
        if (rg < N) {
            const float sr = sref[t] + *batt_p;
            float e[8], mx = -1e30f;
#pragma unroll
            for (int h = 0; h < 8; ++h) {
                const float s = 1.f / (1.f + expf(-(sx[t * 8 + h] + sr)));
                e[h] = s; mx = fmaxf(mx, s);
            }
            float sum = 0.f;
#pragma unroll
            for (int h = 0; h < 8; ++h) { e[h] = expf(e[h] - mx); sum += e[h]; }
            const float inv = 1.f / sum;
#pragma unroll
            for (int h = 0; h < 8; ++h) wsm[(size_t)rg * 8 + h] = e[h] * inv;
        }
    }
}

// ---------------------------------------------------------------------------
// K2: agg = sum_h wsm[:,h]*feats[h] (fp32) -> AGf (A-frag order);
//     h_o = prelu(agg@O1+bo1) -> HOf (A-frag order); out = h_o@O2 + bo2.
// 64 rows/block, 256 threads. All B-frags direct from packed frames (L2).
// ---------------------------------------------------------------------------
__global__ __launch_bounds__(256) void k2_kernel(
    const float* __restrict__ feats, const float* __restrict__ wsm,
    const bf16* __restrict__ o1p, const bf16* __restrict__ o2p,
    const float* __restrict__ bo1, const float* __restrict__ a_out_p,
    const float* __restrict__ bo2, float* __restrict__ out, int N)
{
    union __align__(16) U2 {
        bf16 AGf[16 * 512];   // 16 frames (c*4+i): 16 KB
        bf16 HOf[32 * 512];   // 32 frames (kt*4+i): 32 KB
    };
    __shared__ U2 u;
    __shared__ float wsl[512];

    const int t = threadIdx.x;
    const int lane = t & 63;
    const int cg = t >> 6;
    const int row0 = blockIdx.x * 64;
    const int m = lane & 15, q = lane >> 4;

    for (int i = t; i < 512; i += 256) {
        const int rg = min(row0 + (i >> 3), N - 1);
        wsl[i] = wsm[(size_t)rg * 8 + (i & 7)];
    }
    __syncthreads();

    // ---- weighted hop aggregation (fp32) -> AGf A-frag order ----
    {
        const int r = t >> 2;              // row 0..63
        const int c = t & 3;               // 32-feature chunk == kt of GEMM3
        const int rg = min(row0 + r, N - 1);
        f32x4 a4[8] = {};
#pragma unroll
        for (int h = 0; h < 8; ++h) {
            const float wgt = wsl[r * 8 + h];
            const f32x4* p4 = (const f32x4*)(feats + ((size_t)h * N + rg) * N_F + c * 32);
#pragma unroll
            for (int qq = 0; qq < 8; ++qq) a4[qq] += wgt * p4[qq];
        }
#pragma unroll
        for (int qq = 0; qq < 4; ++qq) {   // qq = quad (k-chunk of 8)
            bf16x8 av;
#pragma unroll
            for (int e = 0; e < 8; ++e) av[e] = (bf16)a4[(qq << 1) + (e >> 2)][e & 3];
            *(bf16x8*)&u.AGf[((((c << 2) + (r >> 4)) << 9) + (((r & 15) | (qq << 4)) << 3))] = av;
        }
    }
    __syncthreads();

    // ---- GEMM3: h_o = prelu(agg @ O1 + bo1, a_out)  [K=128 -> 4 kt] ----
    f32x4 acc3[4][4] = {};
    for (int kt = 0; kt < 4; ++kt) {
        bf16x8 af[4], bfr[4];
#pragma unroll
        for (int i = 0; i < 4; ++i)
            af[i] = *(bf16x8*)&u.AGf[(((kt << 2) + i) << 9) + (lane << 3)];
#pragma unroll
        for (int j = 0; j < 4; ++j)
            bfr[j] = *(const bf16x8*)&o1p[((size_t)((kt << 4) + (cg << 2) + j) * 64 + lane) * 8];
#pragma unroll
        for (int i = 0; i < 4; ++i)
#pragma unroll
            for (int j = 0; j < 4; ++j)
                acc3[i][j] = mfma16(af[i], bfr[j], acc3[i][j]);
    }
    __syncthreads();   // all AGf reads done before HOf overwrites the union

    const float aout = *a_out_p;
#pragma unroll
    for (int j = 0; j < 4; ++j) {
        const int colg = (cg << 6) + (j << 4) + m;
        const float bias = bo1[colg];
#pragma unroll
        for (int i = 0; i < 4; ++i)
#pragma unroll
            for (int r = 0; r < 4; ++r) {
                const int row = (i << 4) + (q << 2) + r;
                float v = acc3[i][j][r] + bias;
                v = v >= 0.f ? v : aout * v;
                u.HOf[frag_addr(row, colg)] = (bf16)v;
            }
    }
    __syncthreads();

    // ---- GEMM4: out = h_o @ O2 + bo2  [K=256 -> 8 kt; wave cg -> 16 cols] ----
    f32x4 acc4[4] = {};
    for (int kt = 0; kt < 8; ++kt) {
        const bf16x8 b = *(const bf16x8*)&o2p[((size_t)((kt << 2) + cg) * 64 + lane) * 8];
#pragma unroll
        for (int i = 0; i < 4; ++i) {
            const bf16x8 a = *(bf16x8*)&u.HOf[(((kt << 2) + i) << 9) + (lane << 3)];
            acc4[i] = mfma16(a, b, acc4[i]);
        }
    }
    {
        const int colg = (cg << 4) + m;
        const float bv = bo2[colg];
#pragma unroll
        for (int i = 0; i < 4; ++i)
#pragma unroll
            for (int r = 0; r < 4; ++r) {
                const int rg = row0 + (i << 4) + (q << 2) + r;
                if (rg < N) out[(size_t)rg * 64 + colg] = acc4[i][r] + bv;
            }
    }
}

extern "C" void kernel_launch(void* const* d_in, const int* in_sizes, int n_in,
                              void* d_out, int out_size, void* d_ws, size_t ws_size,
                              hipStream_t stream) {
    const float* feats  = (const float*)d_in[0];
    const float* W1     = (const float*)d_in[1];
    const float* b1     = (const float*)d_in[2];
    const float* W2     = (const float*)d_in[3];
    const float* b2     = (const float*)d_in[4];
    const float* a_jk   = (const float*)d_in[5];
    const float* a_main = (const float*)d_in[6];
    const float* a_out  = (const float*)d_in[7];
    const float* wref   = (const float*)d_in[8];
    const float* wax    = (const float*)d_in[9];
    const float* batt   = (const float*)d_in[10];
    const float* O1     = (const float*)d_in[11];
    const float* bo1    = (const float*)d_in[12];
    const float* O2     = (const float*)d_in[13];
    const float* bo2    = (const float*)d_in[14];

    const int N = in_sizes[0] / (N_HOPS * N_F);

    char* ws = (char*)d_ws;
    bf16* p1 = (bf16*)ws;                   // 524288 B  (W_jk1 packed)
    bf16* p2 = (bf16*)(ws + 524288);        // 131072 B  (W_jk2 packed)
    bf16* p3 = (bf16*)(ws + 655360);        // 65536 B   (W_o1 packed)
    bf16* p4 = (bf16*)(ws + 720896);        // 32768 B   (W_o2 packed)
    float* wsm = (float*)(ws + 753664);     // N*8*4 B   (softmax hop weights)

    pack_weights<<<184, 256, 0, stream>>>(W1, W2, O1, O2, p1, p2, p3, p4);
    const int nb = (N + 63) / 64;
    k1_kernel<<<nb, 256, 0, stream>>>(feats, p1, p2, b1, b2, a_jk, a_main,
                                      wref, wax, batt, wsm, N);
    k2_kernel<<<nb, 256, 0, stream>>>(feats, wsm, p3, p4, bo1, a_out, bo2,
                                      (float*)d_out, N);
}